// Round 1
// baseline (113193.445 us; speedup 1.0000x reference)
//
#include <hip/hip_runtime.h>
#include <hip/hip_fp16.h>

// ============================================================================
// ChunkParallelGRU on MI355X (gfx950)
//
// Decomposition:
//   z = sig(x@Wzx + bz + h@Wzh)   r = sig(x@Wrx + br + h@Wrh)
//   hc = tanh(x@Whx + bh + (r*h)@Whh)
//   h_new = (1-z)h + z*hc ;  h_next = boundary? tanh(h_new@Wp+bp) : h_new
//
// Kernel plan (all f16 operands, fp32 accum via mfma_f32_16x16x32_f16):
//   1) pack_wxT  : W*[0:1024,:] -> wxT[3072][1024] f16 (transposed, K-contig)
//   2) pack_wrec : W*[1024:2048,:] + Wp -> per-wg MFMA B-fragment images
//   3) init_misc : h0 -> A-fragment image (event 0), zero sync flags
//   4) xproj_gemm: Xtmp[32768][3072] = x @ wxT^T + bias   (parallel, MFMA)
//   5) gru_seq   : persistent kernel, 4 groups x 64 wgs x 256 thr
//        group g handles batch rows [16g,16g+16); wg j owns 16-col slice of
//        each weight matrix, held in VGPRs (wave w = matrix w).
//        h/r exchanged via global buffers in A-fragment order; flag barriers.
//
// MFMA 16x16x32 f16 layouts (m89-verified per guide):
//   A-frag: lane l holds A[m=l&15][k=(l>>4)*8+e], e=0..7
//   B-frag: lane l holds B[k=(l>>4)*8+e][n=l&15]
//   C/D   : lane l reg i = C[row=(l>>4)*4+i][col=l&15]
// ============================================================================

typedef _Float16 half8 __attribute__((ext_vector_type(8)));
typedef float    floatx4 __attribute__((ext_vector_type(4)));

#define T_STEPS 512
#define HD 1024

// ---------------------------------------------------------------------------
// flag polling: 64 lanes each poll one wg's flag (agent scope acquire)
// ---------------------------------------------------------------------------
__device__ __forceinline__ void poll_ge(unsigned* f, unsigned target, int lane) {
    while (__hip_atomic_load(f + lane, __ATOMIC_ACQUIRE, __HIP_MEMORY_SCOPE_AGENT) < target) {
        __builtin_amdgcn_s_sleep(1);
    }
}

// ---------------------------------------------------------------------------
// 1) transpose+convert x-part of Wz/Wr/Wh -> wxT[n=3072][k=1024] f16
// ---------------------------------------------------------------------------
__global__ void pack_wxT(const float* __restrict__ Wz, const float* __restrict__ Wr,
                         const float* __restrict__ Wh, _Float16* __restrict__ wxT) {
    __shared__ float tile[64][65];
    const int k0 = blockIdx.x * 64;
    const int c0 = blockIdx.y * 64;
    const int gate = blockIdx.z;
    const float* W = (gate == 0) ? Wz : ((gate == 1) ? Wr : Wh);
    const int tid = threadIdx.x;
    const int tc = tid & 63;
    const int tr = tid >> 6;  // 0..3
#pragma unroll
    for (int rr = 0; rr < 16; ++rr) {
        int kr = rr * 4 + tr;
        tile[kr][tc] = W[(size_t)(k0 + kr) * 1024 + c0 + tc];
    }
    __syncthreads();
#pragma unroll
    for (int rr = 0; rr < 16; ++rr) {
        int nr = rr * 4 + tr;
        wxT[(size_t)(gate * 1024 + c0 + nr) * 1024 + k0 + tc] = (_Float16)tile[tc][nr];
    }
}

// ---------------------------------------------------------------------------
// 2) pack recurrent weights (h-part rows 1024..2047 of Wz/Wr/Wh, plus Wp)
//    into B-fragment order: wpack[((j*4+mat)*32+kk)*64+lane][e]
//    element = W_mat[k = kk*32+(lane>>4)*8+e][n = j*16+(lane&15)]
// ---------------------------------------------------------------------------
__global__ void pack_wrec(const float* __restrict__ Wz, const float* __restrict__ Wr,
                          const float* __restrict__ Wh, const float* __restrict__ Wp,
                          _Float16* __restrict__ wpack) {
    int idx = blockIdx.x * 256 + threadIdx.x;  // 0..524287
    int mat = (idx >> 11) & 3;
    int kk = (idx >> 6) & 31;
    int lane = idx & 63;
    int j = idx >> 13;
    int n = j * 16 + (lane & 15);
    int kb = kk * 32 + (lane >> 4) * 8;
    const float* W = (mat == 0) ? Wz : ((mat == 1) ? Wr : ((mat == 2) ? Wh : Wp));
    size_t rowoff = (mat < 3) ? 1024 : 0;  // h-part of the 2048-row matrices
#pragma unroll
    for (int e = 0; e < 8; ++e) {
        wpack[(size_t)idx * 8 + e] = (_Float16)W[(rowoff + kb + e) * 1024 + n];
    }
}

// ---------------------------------------------------------------------------
// 3) h0 -> A-fragment image (event 0 = hfrag buffer parity 0); zero flags
//    hfrag element (g, kk, lane, e) = h0[g*16 + (lane&15)][kk*32+(lane>>4)*8+e]
// ---------------------------------------------------------------------------
__global__ void init_misc(const float* __restrict__ h0, _Float16* __restrict__ hfrag,
                          unsigned* __restrict__ flags) {
    int idx = blockIdx.x * 256 + threadIdx.x;  // 0..8191
    int g = idx >> 11;
    int kk = (idx >> 6) & 31;
    int lane = idx & 63;
    int b = lane & 15;
    int kb = kk * 32 + (lane >> 4) * 8;
#pragma unroll
    for (int e = 0; e < 8; ++e)
        hfrag[(size_t)g * 16384 + (size_t)(kk * 64 + lane) * 8 + e] =
            (_Float16)h0[(size_t)(g * 16 + b) * 1024 + kb + e];
    if (blockIdx.x == 0) {
        flags[threadIdx.x] = 0;        // flags_h [4][64]
        flags[threadIdx.x + 256] = 0;  // flags_r
        flags[threadIdx.x + 512] = 0;  // flags_n
    }
}

// ---------------------------------------------------------------------------
// 4) Xtmp[32768][3072] = x @ wxT^T + bias(gate), f16 out.
//    128x128 tile, BK=32, 4 waves x (64x64 = 4x4 16x16 tiles). LDS padded +8
//    halves (80B rows -> <=2-way bank aliasing = free).
// ---------------------------------------------------------------------------
__global__ __launch_bounds__(256) void xproj_gemm(
    const float* __restrict__ x, const _Float16* __restrict__ wxT,
    const float* __restrict__ bz, const float* __restrict__ br,
    const float* __restrict__ bh, _Float16* __restrict__ Xtmp) {
    __shared__ _Float16 Als[128][40];
    __shared__ _Float16 Bls[128][40];
    const int tid = threadIdx.x;
    const int n0 = blockIdx.x * 128;
    const int m0 = blockIdx.y * 128;
    const int lane = tid & 63;
    const int wave = tid >> 6;
    const int lm = lane & 15, lq = lane >> 4;
    const int wm = (wave >> 1) * 64, wn = (wave & 1) * 64;
    const int srow = tid >> 1;
    const int shalf = (tid & 1) * 16;

    floatx4 acc[4][4];
#pragma unroll
    for (int mi = 0; mi < 4; ++mi)
#pragma unroll
        for (int ni = 0; ni < 4; ++ni) acc[mi][ni] = (floatx4){0.f, 0.f, 0.f, 0.f};

    for (int k0 = 0; k0 < 1024; k0 += 32) {
        {  // stage A (fp32 -> f16) and B
            const float* src = x + (size_t)(m0 + srow) * 1024 + k0 + shalf;
            float4 p0 = ((const float4*)src)[0];
            float4 p1 = ((const float4*)src)[1];
            float4 p2 = ((const float4*)src)[2];
            float4 p3 = ((const float4*)src)[3];
            half8 h0v = {(_Float16)p0.x, (_Float16)p0.y, (_Float16)p0.z, (_Float16)p0.w,
                         (_Float16)p1.x, (_Float16)p1.y, (_Float16)p1.z, (_Float16)p1.w};
            half8 h1v = {(_Float16)p2.x, (_Float16)p2.y, (_Float16)p2.z, (_Float16)p2.w,
                         (_Float16)p3.x, (_Float16)p3.y, (_Float16)p3.z, (_Float16)p3.w};
            *(half8*)&Als[srow][shalf] = h0v;
            *(half8*)&Als[srow][shalf + 8] = h1v;
            const _Float16* bsrc = wxT + (size_t)(n0 + srow) * 1024 + k0 + shalf;
            *(half8*)&Bls[srow][shalf] = ((const half8*)bsrc)[0];
            *(half8*)&Bls[srow][shalf + 8] = ((const half8*)bsrc)[1];
        }
        __syncthreads();
        half8 af[4], bf[4];
#pragma unroll
        for (int mi = 0; mi < 4; ++mi) af[mi] = *(const half8*)&Als[wm + mi * 16 + lm][lq * 8];
#pragma unroll
        for (int ni = 0; ni < 4; ++ni) bf[ni] = *(const half8*)&Bls[wn + ni * 16 + lm][lq * 8];
#pragma unroll
        for (int mi = 0; mi < 4; ++mi)
#pragma unroll
            for (int ni = 0; ni < 4; ++ni)
                acc[mi][ni] = __builtin_amdgcn_mfma_f32_16x16x32_f16(af[mi], bf[ni], acc[mi][ni], 0, 0, 0);
        __syncthreads();
    }
// epilogue: +bias, f16 store (lanes 0-15 = consecutive cols -> 32B chunks)
#pragma unroll
    for (int mi = 0; mi < 4; ++mi) {
#pragma unroll
        for (int i = 0; i < 4; ++i) {
            int row = m0 + wm + mi * 16 + lq * 4 + i;
#pragma unroll
            for (int ni = 0; ni < 4; ++ni) {
                int col = n0 + wn + ni * 16 + lm;
                float bias = (col < 1024) ? bz[col] : ((col < 2048) ? br[col - 1024] : bh[col - 2048]);
                Xtmp[(size_t)row * 3072 + col] = (_Float16)(acc[mi][ni][i] + bias);
            }
        }
    }
}

// ---------------------------------------------------------------------------
// 5) persistent sequential kernel.
//    grid 256 wgs x 256 thr.  g = wg&3 (batch group, rows 16g..16g+16),
//    j = wg>>2 (16-col slice).  wave = matrix (0=z,1=r,2=hc,3=p), weights in
//    VGPRs (128/wave).  Per step:
//      waves 0,1: poll h(t) -> MFMA -> sigmoid; w0 keeps z in LDS, w1
//                 publishes r-frags + flag_r=t+1
//      S1 = __syncthreads
//      wave 2: poll h(t) (also closes WAR on buf[(t+1)&1]) + r(t+1) ->
//              rh MFMA -> tanh -> h_new; write ys; publish h or hn frags
//      wave 3 (boundary): poll hn -> Wp MFMA -> tanh -> publish h, flag_h
//    h double-buffered by parity of t; r/hn single (WAR closed by flags).
// ---------------------------------------------------------------------------
__global__ __launch_bounds__(256, 1) void gru_seq_kernel(
    const _Float16* __restrict__ Xtmp, const _Float16* __restrict__ wpack,
    _Float16* __restrict__ hfrag,   // [2][4][16384]
    _Float16* __restrict__ rfrag,   // [4][16384]
    _Float16* __restrict__ hnfrag,  // [4][16384]
    unsigned* flags_h, unsigned* flags_r, unsigned* flags_n,
    const float* __restrict__ bp, float* __restrict__ out) {
    const int wg = blockIdx.x;
    const int g = wg & 3;
    const int j = wg >> 2;
    const int tid = threadIdx.x;
    const int wave = tid >> 6;
    const int lane = tid & 63;
    const int lm = lane & 15;
    const int lq = lane >> 4;

    __shared__ float zbuf[256];

    // persistent B-fragments for this wave's matrix
    half8 W[32];
    {
        const half8* wp = (const half8*)wpack + (size_t)((j * 4 + wave) * 32) * 64 + lane;
#pragma unroll
        for (int kk = 0; kk < 32; ++kk) W[kk] = wp[kk * 64];
    }
    const float bpl = bp[j * 16 + lm];

    unsigned* fh = flags_h + g * 64;
    unsigned* fr = flags_r + g * 64;
    unsigned* fn = flags_n + g * 64;

    // fragment address pieces for this wg's 16-col slice (k = j*16 + lm)
    const int kkd = j >> 1;
    const int sub = ((j & 1) << 1) | (lm >> 3);
    const int e = lm & 7;
    const int fragoff = (kkd * 64 + sub * 16) * 8 + e;  // add b*8

    for (int t = 0; t < T_STEPS; ++t) {
        const bool boundary = ((t & 3) == 3) && (t != T_STEPS - 1);

        if (wave < 2) {
            poll_ge(fh, (unsigned)t, lane);
            float xv[4];
#pragma unroll
            for (int i = 0; i < 4; ++i) {
                int b = lq * 4 + i;
                xv[i] = (float)Xtmp[(size_t)((g * 16 + b) * 512 + t) * 3072 + wave * 1024 + j * 16 + lm];
            }
            const half8* ha = (const half8*)hfrag + (size_t)((t & 1) * 4 + g) * 2048 + lane;
            floatx4 acc = {0.f, 0.f, 0.f, 0.f};
#pragma unroll
            for (int kk = 0; kk < 32; ++kk)
                acc = __builtin_amdgcn_mfma_f32_16x16x32_f16(ha[kk * 64], W[kk], acc, 0, 0, 0);
            if (wave == 0) {
#pragma unroll
                for (int i = 0; i < 4; ++i)
                    zbuf[lane * 4 + i] = 1.f / (1.f + __expf(-(acc[i] + xv[i])));
            } else {
                _Float16* rf = rfrag + (size_t)g * 16384;
#pragma unroll
                for (int i = 0; i < 4; ++i) {
                    float rv = 1.f / (1.f + __expf(-(acc[i] + xv[i])));
                    rf[fragoff + (lq * 4 + i) * 8] = (_Float16)rv;
                }
                __threadfence();
                if (lane == 0)
                    __hip_atomic_store(fr + j, (unsigned)(t + 1), __ATOMIC_RELAXED, __HIP_MEMORY_SCOPE_AGENT);
            }
        }
        __syncthreads();  // S1
        if (wave == 2) {
            poll_ge(fh, (unsigned)t, lane);       // h(t) ready AND event t-1 readers done (WAR)
            poll_ge(fr, (unsigned)(t + 1), lane); // r(t) ready
            float xv[4];
#pragma unroll
            for (int i = 0; i < 4; ++i) {
                int b = lq * 4 + i;
                xv[i] = (float)Xtmp[(size_t)((g * 16 + b) * 512 + t) * 3072 + 2048 + j * 16 + lm];
            }
            const half8* ha = (const half8*)hfrag + (size_t)((t & 1) * 4 + g) * 2048 + lane;
            const half8* ra = (const half8*)rfrag + (size_t)g * 2048 + lane;
            floatx4 acc = {0.f, 0.f, 0.f, 0.f};
#pragma unroll
            for (int kk = 0; kk < 32; ++kk) {
                half8 rh = ha[kk * 64] * ra[kk * 64];
                acc = __builtin_amdgcn_mfma_f32_16x16x32_f16(rh, W[kk], acc, 0, 0, 0);
            }
            const _Float16* hf = hfrag + (size_t)((t & 1) * 4 + g) * 16384;
            _Float16* dst = boundary ? (hnfrag + (size_t)g * 16384)
                                     : (hfrag + (size_t)(((t + 1) & 1) * 4 + g) * 16384);
#pragma unroll
            for (int i = 0; i < 4; ++i) {
                int b = lq * 4 + i;
                float hc = tanhf(acc[i] + xv[i]);
                float z = zbuf[lane * 4 + i];
                float hp = (float)hf[fragoff + b * 8];
                float hn = (1.f - z) * hp + z * hc;
                __builtin_nontemporal_store(hn, &out[(size_t)((g * 16 + b) * 512 + t) * 1024 + j * 16 + lm]);
                dst[fragoff + b * 8] = (_Float16)hn;
            }
            if (t < T_STEPS - 1) {
                __threadfence();
                if (lane == 0) {
                    if (boundary)
                        __hip_atomic_store(fn + j, (unsigned)(t + 1), __ATOMIC_RELAXED, __HIP_MEMORY_SCOPE_AGENT);
                    else
                        __hip_atomic_store(fh + j, (unsigned)(t + 1), __ATOMIC_RELAXED, __HIP_MEMORY_SCOPE_AGENT);
                }
            }
        } else if (wave == 3 && boundary) {
            poll_ge(fn, (unsigned)(t + 1), lane);
            const half8* na = (const half8*)hnfrag + (size_t)g * 2048 + lane;
            floatx4 acc = {0.f, 0.f, 0.f, 0.f};
#pragma unroll
            for (int kk = 0; kk < 32; ++kk)
                acc = __builtin_amdgcn_mfma_f32_16x16x32_f16(na[kk * 64], W[kk], acc, 0, 0, 0);
            _Float16* dst = hfrag + (size_t)(((t + 1) & 1) * 4 + g) * 16384;
#pragma unroll
            for (int i = 0; i < 4; ++i) {
                float hv = tanhf(acc[i] + bpl);
                dst[fragoff + (lq * 4 + i) * 8] = (_Float16)hv;
            }
            __threadfence();
            if (lane == 0)
                __hip_atomic_store(fh + j, (unsigned)(t + 1), __ATOMIC_RELAXED, __HIP_MEMORY_SCOPE_AGENT);
        }
    }
}

// ---------------------------------------------------------------------------
// host launcher
// ---------------------------------------------------------------------------
extern "C" void kernel_launch(void* const* d_in, const int* in_sizes, int n_in,
                              void* d_out, int out_size, void* d_ws, size_t ws_size,
                              hipStream_t stream) {
    (void)in_sizes; (void)n_in; (void)out_size; (void)ws_size;
    const float* x  = (const float*)d_in[0];
    const float* h0 = (const float*)d_in[1];
    const float* Wz = (const float*)d_in[2];
    const float* bz = (const float*)d_in[3];
    const float* Wr = (const float*)d_in[4];
    const float* br = (const float*)d_in[5];
    const float* Wh = (const float*)d_in[6];
    const float* bh = (const float*)d_in[7];
    const float* Wp = (const float*)d_in[8];
    const float* bp = (const float*)d_in[9];
    float* out = (float*)d_out;

    // workspace layout (total ~216.5 MB, all 16B-aligned offsets)
    char* ws = (char*)d_ws;
    _Float16* wxT    = (_Float16*)(ws);                // 6,291,456 B
    _Float16* wpack  = (_Float16*)(ws + 6291456);      // 8,388,608 B
    _Float16* Xtmp   = (_Float16*)(ws + 14680064);     // 201,326,592 B
    _Float16* hfrag  = (_Float16*)(ws + 216006656);    // 262,144 B  [2][4][16384]
    _Float16* rfrag  = (_Float16*)(ws + 216268800);    // 131,072 B  [4][16384]
    _Float16* hnfrag = (_Float16*)(ws + 216399872);    // 131,072 B  [4][16384]
    unsigned* flags  = (unsigned*)(ws + 216530944);    // 3,072 B (h|r|n x 256)
    unsigned* flags_h = flags;
    unsigned* flags_r = flags + 256;
    unsigned* flags_n = flags + 512;

    pack_wxT<<<dim3(16, 16, 3), 256, 0, stream>>>(Wz, Wr, Wh, wxT);
    pack_wrec<<<2048, 256, 0, stream>>>(Wz, Wr, Wh, Wp, wpack);
    init_misc<<<32, 256, 0, stream>>>(h0, hfrag, flags);
    xproj_gemm<<<dim3(24, 256), 256, 0, stream>>>(x, wxT, bz, br, bh, Xtmp);
    gru_seq_kernel<<<256, 256, 0, stream>>>(Xtmp, wpack, hfrag, rfrag, hnfrag,
                                            flags_h, flags_r, flags_n, bp, out);
}

// Round 2
// 12539.217 us; speedup vs baseline: 9.0272x; 9.0272x over previous
//
#include <hip/hip_runtime.h>
#include <hip/hip_fp16.h>

// ============================================================================
// ChunkParallelGRU on MI355X (gfx950) — R2
//
// R1 failure mode: ACQUIRE atomics (buffer_inv) + __threadfence (buffer_wbl2)
// per step = L2 cache-maintenance storm -> 221 us/step. R2: all cross-wg
// traffic via RELAXED agent-scope atomics (per-access sc bits, IF$-coherent,
// no cache nukes); manual release via `s_waitcnt vmcnt(0)` before flag store.
//
// Structure (unchanged from R1): xproj GEMM precomputes x@W + bias for all
// t; persistent gru_seq kernel, 4 groups x 64 wgs; wg (g,j) owns 16-col
// slice j of each matrix, weights in VGPRs (wave w = matrix w: z,r,hc,Wp).
// h/r exchanged through IF$ in MFMA A-fragment order.
//
// New in R2:
//  - h A-frags staged once per wg via LDS (waves 0/1 load 16KB halves each)
//  - wave2 keeps own h-slice in f32 registers; boundary handoff via pbuf LDS
//  - Xtmp re-laid out as [(g*64+j)*3+mat][t][c*16+b] -> one 8B/lane read
//  - producer stores: LDS 16x16 transpose -> one 8B relaxed store per lane
//  - out[] stores after flag publish (off the release-waitcnt path)
// ============================================================================

typedef _Float16 half8 __attribute__((ext_vector_type(8)));
typedef _Float16 half4v __attribute__((ext_vector_type(4)));
typedef float    floatx4 __attribute__((ext_vector_type(4)));

#define T_STEPS 512

#define AL(p)    __hip_atomic_load((p), __ATOMIC_RELAXED, __HIP_MEMORY_SCOPE_AGENT)
#define AS(p, v) __hip_atomic_store((p), (v), __ATOMIC_RELAXED, __HIP_MEMORY_SCOPE_AGENT)

union U16 { unsigned long long u[2]; half8 h; };

__device__ __forceinline__ void poll_ge(unsigned* f, unsigned target, int lane) {
    while (AL(f + lane) < target) __builtin_amdgcn_s_sleep(1);
    asm volatile("" ::: "memory");  // keep later mem ops after the spin
}

// ---------------------------------------------------------------------------
// 1) transpose+convert x-part of Wz/Wr/Wh -> wxT[n=3072][k=1024] f16
// ---------------------------------------------------------------------------
__global__ void pack_wxT(const float* __restrict__ Wz, const float* __restrict__ Wr,
                         const float* __restrict__ Wh, _Float16* __restrict__ wxT) {
    __shared__ float tile[64][65];
    const int k0 = blockIdx.x * 64;
    const int c0 = blockIdx.y * 64;
    const int gate = blockIdx.z;
    const float* W = (gate == 0) ? Wz : ((gate == 1) ? Wr : Wh);
    const int tid = threadIdx.x;
    const int tc = tid & 63;
    const int tr = tid >> 6;
#pragma unroll
    for (int rr = 0; rr < 16; ++rr) {
        int kr = rr * 4 + tr;
        tile[kr][tc] = W[(size_t)(k0 + kr) * 1024 + c0 + tc];
    }
    __syncthreads();
#pragma unroll
    for (int rr = 0; rr < 16; ++rr) {
        int nr = rr * 4 + tr;
        wxT[(size_t)(gate * 1024 + c0 + nr) * 1024 + k0 + tc] = (_Float16)tile[tc][nr];
    }
}

// ---------------------------------------------------------------------------
// 2) recurrent weights -> per-wg MFMA B-fragment images
//    wpack[((j*4+mat)*32+kk)*64+lane][e] = W_mat[k=kk*32+(lane>>4)*8+e][n=j*16+(lane&15)]
// ---------------------------------------------------------------------------
__global__ void pack_wrec(const float* __restrict__ Wz, const float* __restrict__ Wr,
                          const float* __restrict__ Wh, const float* __restrict__ Wp,
                          _Float16* __restrict__ wpack) {
    int idx = blockIdx.x * 256 + threadIdx.x;
    int mat = (idx >> 11) & 3;
    int kk = (idx >> 6) & 31;
    int lane = idx & 63;
    int j = idx >> 13;
    int n = j * 16 + (lane & 15);
    int kb = kk * 32 + (lane >> 4) * 8;
    const float* W = (mat == 0) ? Wz : ((mat == 1) ? Wr : ((mat == 2) ? Wh : Wp));
    size_t rowoff = (mat < 3) ? 1024 : 0;
#pragma unroll
    for (int e = 0; e < 8; ++e)
        wpack[(size_t)idx * 8 + e] = (_Float16)W[(rowoff + kb + e) * 1024 + n];
}

// ---------------------------------------------------------------------------
// 3) h0 -> A-fragment image (event 0); zero sync flags
// ---------------------------------------------------------------------------
__global__ void init_misc(const float* __restrict__ h0, _Float16* __restrict__ hfrag,
                          unsigned* __restrict__ flags) {
    int idx = blockIdx.x * 256 + threadIdx.x;  // 0..8191
    int g = idx >> 11;
    int kk = (idx >> 6) & 31;
    int lane = idx & 63;
    int b = lane & 15;
    int kb = kk * 32 + (lane >> 4) * 8;
#pragma unroll
    for (int e = 0; e < 8; ++e)
        hfrag[(size_t)g * 16384 + (size_t)(kk * 64 + lane) * 8 + e] =
            (_Float16)h0[(size_t)(g * 16 + b) * 1024 + kb + e];
    if (blockIdx.x == 0) {
        flags[threadIdx.x] = 0;
        flags[threadIdx.x + 256] = 0;
        flags[threadIdx.x + 512] = 0;
    }
}

// ---------------------------------------------------------------------------
// 4) Xtmp = x @ wxT^T + bias, stored as [(g*64+j)*3+mat][t][c*16+b] f16
// ---------------------------------------------------------------------------
__global__ __launch_bounds__(256) void xproj_gemm(
    const float* __restrict__ x, const _Float16* __restrict__ wxT,
    const float* __restrict__ bz, const float* __restrict__ br,
    const float* __restrict__ bh, _Float16* __restrict__ Xtmp) {
    __shared__ _Float16 Als[128][40];
    __shared__ _Float16 Bls[128][40];
    const int tid = threadIdx.x;
    const int n0 = blockIdx.x * 128;
    const int m0 = blockIdx.y * 128;
    const int lane = tid & 63;
    const int wave = tid >> 6;
    const int lm = lane & 15, lq = lane >> 4;
    const int wm = (wave >> 1) * 64, wn = (wave & 1) * 64;
    const int srow = tid >> 1;
    const int shalf = (tid & 1) * 16;

    floatx4 acc[4][4];
#pragma unroll
    for (int mi = 0; mi < 4; ++mi)
#pragma unroll
        for (int ni = 0; ni < 4; ++ni) acc[mi][ni] = (floatx4){0.f, 0.f, 0.f, 0.f};

    for (int k0 = 0; k0 < 1024; k0 += 32) {
        {
            const float* src = x + (size_t)(m0 + srow) * 1024 + k0 + shalf;
            float4 p0 = ((const float4*)src)[0];
            float4 p1 = ((const float4*)src)[1];
            float4 p2 = ((const float4*)src)[2];
            float4 p3 = ((const float4*)src)[3];
            half8 h0v = {(_Float16)p0.x, (_Float16)p0.y, (_Float16)p0.z, (_Float16)p0.w,
                         (_Float16)p1.x, (_Float16)p1.y, (_Float16)p1.z, (_Float16)p1.w};
            half8 h1v = {(_Float16)p2.x, (_Float16)p2.y, (_Float16)p2.z, (_Float16)p2.w,
                         (_Float16)p3.x, (_Float16)p3.y, (_Float16)p3.z, (_Float16)p3.w};
            *(half8*)&Als[srow][shalf] = h0v;
            *(half8*)&Als[srow][shalf + 8] = h1v;
            const _Float16* bsrc = wxT + (size_t)(n0 + srow) * 1024 + k0 + shalf;
            *(half8*)&Bls[srow][shalf] = ((const half8*)bsrc)[0];
            *(half8*)&Bls[srow][shalf + 8] = ((const half8*)bsrc)[1];
        }
        __syncthreads();
        half8 af[4], bf[4];
#pragma unroll
        for (int mi = 0; mi < 4; ++mi) af[mi] = *(const half8*)&Als[wm + mi * 16 + lm][lq * 8];
#pragma unroll
        for (int ni = 0; ni < 4; ++ni) bf[ni] = *(const half8*)&Bls[wn + ni * 16 + lm][lq * 8];
#pragma unroll
        for (int mi = 0; mi < 4; ++mi)
#pragma unroll
            for (int ni = 0; ni < 4; ++ni)
                acc[mi][ni] = __builtin_amdgcn_mfma_f32_16x16x32_f16(af[mi], bf[ni], acc[mi][ni], 0, 0, 0);
        __syncthreads();
    }
    // epilogue -> new layout: idx = (((g*64+j)*3+mat)*512 + t)*256 + c*16 + b
#pragma unroll
    for (int mi = 0; mi < 4; ++mi) {
#pragma unroll
        for (int i = 0; i < 4; ++i) {
            int row = m0 + wm + mi * 16 + lq * 4 + i;  // (g*16+b)*512 + t
            int t = row & 511;
            int bglob = row >> 9;
            int g = bglob >> 4, b = bglob & 15;
#pragma unroll
            for (int ni = 0; ni < 4; ++ni) {
                int col = n0 + wn + ni * 16 + lm;  // mat*1024 + j*16 + c
                int mat = col >> 10;
                int jc = col - mat * 1024;
                int jj = jc >> 4, c = jc & 15;
                float bias = (mat == 0) ? bz[jc] : ((mat == 1) ? br[jc] : bh[jc]);
                size_t idx = ((((size_t)(g * 64 + jj) * 3 + mat) * 512 + t) << 8) + c * 16 + b;
                Xtmp[idx] = (_Float16)(acc[mi][ni][i] + bias);
            }
        }
    }
}

// ---------------------------------------------------------------------------
// 5) persistent sequential kernel (see header comment)
// ---------------------------------------------------------------------------
__global__ __launch_bounds__(256, 1) void gru_seq_kernel(
    const _Float16* __restrict__ Xtmp, const _Float16* __restrict__ wpack,
    const float* __restrict__ h0,
    _Float16* __restrict__ hfrag,   // [2][4][16384]
    _Float16* __restrict__ rfrag,   // [4][16384]
    _Float16* __restrict__ hnfrag,  // [4][16384]
    unsigned* flags_h, unsigned* flags_r, unsigned* flags_n,
    const float* __restrict__ bp, float* __restrict__ out) {
    const int wg = blockIdx.x;
    const int g = wg & 3;
    const int j = wg >> 2;
    const int tid = threadIdx.x;
    const int wave = tid >> 6;
    const int lane = tid & 63;
    const int lm = lane & 15;
    const int lq = lane >> 4;

    __shared__ __align__(16) _Float16 als[32 * 64 * 8];  // 32KB staged h A-frags
    __shared__ float zbuf[256];
    __shared__ float pbuf[256];
    __shared__ _Float16 rbuf[256];
    __shared__ _Float16 hbuf[256];
    __shared__ _Float16 nbuf[256];

    // persistent B-fragments: wave w holds matrix w (z,r,hc,Wp), 128 VGPR
    half8 W[32];
    {
        const half8* wp = (const half8*)wpack + (size_t)((j * 4 + wave) * 32) * 64 + lane;
#pragma unroll
        for (int kk = 0; kk < 32; ++kk) W[kk] = wp[kk * 64];
    }
    const float bpl = bp[j * 16 + lm];

    unsigned* fh = flags_h + g * 64;
    unsigned* fr = flags_r + g * 64;
    unsigned* fn = flags_n + g * 64;

    // transpose-store lane roles: one 8B chunk per lane covers the wg's
    // 16x16 output slice in A-frag order
    const int kkd = j >> 1;
    const int s_ = lane >> 5;
    const int b_ = (lane >> 1) & 15;
    const int hp_ = lane & 1;
    const size_t fidx = (size_t)((kkd * 64 + (2 * (j & 1) + s_) * 16 + b_) * 2 + hp_);
    const int ldsrd = b_ * 16 + s_ * 8 + hp_ * 4;  // halves offset in 16x16 buf

    // wave2 persistent h registers (own slice: b=lq*4+i, col=j*16+lm)
    float hreg[4];
    if (wave == 2) {
#pragma unroll
        for (int i = 0; i < 4; ++i)
            hreg[i] = h0[(size_t)(g * 16 + lq * 4 + i) * 1024 + j * 16 + lm];
    }

    unsigned long long* als8 = (unsigned long long*)als;

    for (int t = 0; t < T_STEPS; ++t) {
        const bool boundary = ((t & 3) == 3) && (t != T_STEPS - 1);

        // ---- phase A: stage h(t) A-frags into LDS (waves 0,1) ----
        if (wave < 2) {
            poll_ge(fh, (unsigned)t, lane);
            const unsigned long long* hp8 =
                (const unsigned long long*)(hfrag + (size_t)((t & 1) * 4 + g) * 16384);
            unsigned long long tmp[32];
            const int base = wave * 16;
#pragma unroll
            for (int q = 0; q < 16; ++q) {
                int kk = base + q;
                tmp[2 * q] = AL(hp8 + (size_t)(kk * 64 + lane) * 2);
                tmp[2 * q + 1] = AL(hp8 + (size_t)(kk * 64 + lane) * 2 + 1);
            }
#pragma unroll
            for (int q = 0; q < 16; ++q) {
                int kk = base + q;
                als8[(kk * 64 + lane) * 2] = tmp[2 * q];
                als8[(kk * 64 + lane) * 2 + 1] = tmp[2 * q + 1];
            }
        }
        __syncthreads();  // S0: als valid

        // ---- phase B: z and r (waves 0,1) ----
        if (wave < 2) {
            half4v xv4 = *(const half4v*)(Xtmp +
                ((((size_t)(g * 64 + j) * 3 + wave) * 512 + t) << 8) + lm * 16 + lq * 4);
            floatx4 acc = {0.f, 0.f, 0.f, 0.f};
#pragma unroll
            for (int kk = 0; kk < 32; ++kk) {
                half8 av = *(const half8*)&als[(kk * 64 + lane) * 8];
                acc = __builtin_amdgcn_mfma_f32_16x16x32_f16(av, W[kk], acc, 0, 0, 0);
            }
            if (wave == 0) {
#pragma unroll
                for (int i = 0; i < 4; ++i)
                    zbuf[lane * 4 + i] = 1.f / (1.f + __expf(-(acc[i] + (float)xv4[i])));
            } else {
#pragma unroll
                for (int i = 0; i < 4; ++i)
                    rbuf[(lq * 4 + i) * 16 + lm] =
                        (_Float16)(1.f / (1.f + __expf(-(acc[i] + (float)xv4[i]))));
                asm volatile("s_waitcnt lgkmcnt(0)" ::: "memory");
                unsigned long long rv8 = *(const unsigned long long*)&rbuf[ldsrd];
                AS((unsigned long long*)(rfrag + (size_t)g * 16384) + fidx, rv8);
                asm volatile("s_waitcnt vmcnt(0)" ::: "memory");  // release
                if (lane == 0) AS(fr + j, (unsigned)(t + 1));
            }
        }
        __syncthreads();  // S1: zbuf valid

        // ---- phase C: candidate + blend (wave 2) / projection (wave 3) ----
        if (wave == 2) {
            half4v xv4 = *(const half4v*)(Xtmp +
                ((((size_t)(g * 64 + j) * 3 + 2) * 512 + t) << 8) + lm * 16 + lq * 4);
            poll_ge(fr, (unsigned)(t + 1), lane);
            const unsigned long long* rr8 = (const unsigned long long*)(rfrag + (size_t)g * 16384);
            floatx4 acc = {0.f, 0.f, 0.f, 0.f};
#pragma unroll
            for (int kk = 0; kk < 32; ++kk) {
                half8 av = *(const half8*)&als[(kk * 64 + lane) * 8];
                U16 rc;
                rc.u[0] = AL(rr8 + (size_t)(kk * 64 + lane) * 2);
                rc.u[1] = AL(rr8 + (size_t)(kk * 64 + lane) * 2 + 1);
                half8 prod = av * rc.h;
                acc = __builtin_amdgcn_mfma_f32_16x16x32_f16(prod, W[kk], acc, 0, 0, 0);
            }
            const bool post_b = (t > 0) && ((t & 3) == 0);
            float hn_[4];
#pragma unroll
            for (int i = 0; i < 4; ++i) {
                float hp = post_b ? pbuf[(lq * 4 + i) * 16 + lm] : hreg[i];
                float z = zbuf[lane * 4 + i];
                float hc = tanhf(acc[i] + (float)xv4[i]);
                float hn = (1.f - z) * hp + z * hc;
                hn_[i] = hn;
                hreg[i] = hn;
                hbuf[(lq * 4 + i) * 16 + lm] = (_Float16)hn;
            }
            asm volatile("s_waitcnt lgkmcnt(0)" ::: "memory");
            unsigned long long hv8 = *(const unsigned long long*)&hbuf[ldsrd];
            unsigned long long* dst8 = (unsigned long long*)(boundary
                ? (hnfrag + (size_t)g * 16384)
                : (hfrag + (size_t)(((t + 1) & 1) * 4 + g) * 16384));
            AS(dst8 + fidx, hv8);
            asm volatile("s_waitcnt vmcnt(0)" ::: "memory");  // release
            if (t < T_STEPS - 1 && lane == 0) {
                if (boundary) AS(fn + j, (unsigned)(t + 1));
                else          AS(fh + j, (unsigned)(t + 1));
            }
            // out[] stores AFTER flag publish (off the release path)
#pragma unroll
            for (int i = 0; i < 4; ++i)
                __builtin_nontemporal_store(hn_[i],
                    &out[(size_t)((g * 16 + lq * 4 + i) * 512 + t) * 1024 + j * 16 + lm]);
        } else if (wave == 3 && boundary) {
            poll_ge(fn, (unsigned)(t + 1), lane);
            const unsigned long long* nn8 = (const unsigned long long*)(hnfrag + (size_t)g * 16384);
            floatx4 acc = {0.f, 0.f, 0.f, 0.f};
#pragma unroll
            for (int kk = 0; kk < 32; ++kk) {
                U16 nc;
                nc.u[0] = AL(nn8 + (size_t)(kk * 64 + lane) * 2);
                nc.u[1] = AL(nn8 + (size_t)(kk * 64 + lane) * 2 + 1);
                acc = __builtin_amdgcn_mfma_f32_16x16x32_f16(nc.h, W[kk], acc, 0, 0, 0);
            }
#pragma unroll
            for (int i = 0; i < 4; ++i) {
                float hv = tanhf(acc[i] + bpl);
                pbuf[(lq * 4 + i) * 16 + lm] = hv;            // handoff to wave2 (t+1)
                nbuf[(lq * 4 + i) * 16 + lm] = (_Float16)hv;
            }
            asm volatile("s_waitcnt lgkmcnt(0)" ::: "memory");
            unsigned long long nv8 = *(const unsigned long long*)&nbuf[ldsrd];
            AS((unsigned long long*)(hfrag + (size_t)(((t + 1) & 1) * 4 + g) * 16384) + fidx, nv8);
            asm volatile("s_waitcnt vmcnt(0)" ::: "memory");  // release
            if (lane == 0) AS(fh + j, (unsigned)(t + 1));
        }
    }
}

// ---------------------------------------------------------------------------
// host launcher
// ---------------------------------------------------------------------------
extern "C" void kernel_launch(void* const* d_in, const int* in_sizes, int n_in,
                              void* d_out, int out_size, void* d_ws, size_t ws_size,
                              hipStream_t stream) {
    (void)in_sizes; (void)n_in; (void)out_size; (void)ws_size;
    const float* x  = (const float*)d_in[0];
    const float* h0 = (const float*)d_in[1];
    const float* Wz = (const float*)d_in[2];
    const float* bz = (const float*)d_in[3];
    const float* Wr = (const float*)d_in[4];
    const float* br = (const float*)d_in[5];
    const float* Wh = (const float*)d_in[6];
    const float* bh = (const float*)d_in[7];
    const float* Wp = (const float*)d_in[8];
    const float* bp = (const float*)d_in[9];
    float* out = (float*)d_out;

    char* ws = (char*)d_ws;
    _Float16* wxT    = (_Float16*)(ws);                // 6,291,456 B
    _Float16* wpack  = (_Float16*)(ws + 6291456);      // 8,388,608 B
    _Float16* Xtmp   = (_Float16*)(ws + 14680064);     // 201,326,592 B
    _Float16* hfrag  = (_Float16*)(ws + 216006656);    // 262,144 B  [2][4][16384]
    _Float16* rfrag  = (_Float16*)(ws + 216268800);    // 131,072 B  [4][16384]
    _Float16* hnfrag = (_Float16*)(ws + 216399872);    // 131,072 B  [4][16384]
    unsigned* flags  = (unsigned*)(ws + 216530944);    // 3,072 B
    unsigned* flags_h = flags;
    unsigned* flags_r = flags + 256;
    unsigned* flags_n = flags + 512;

    pack_wxT<<<dim3(16, 16, 3), 256, 0, stream>>>(Wz, Wr, Wh, wxT);
    pack_wrec<<<2048, 256, 0, stream>>>(Wz, Wr, Wh, Wp, wpack);
    init_misc<<<32, 256, 0, stream>>>(h0, hfrag, flags);
    xproj_gemm<<<dim3(24, 256), 256, 0, stream>>>(x, wxT, bz, br, bh, Xtmp);
    gru_seq_kernel<<<256, 256, 0, stream>>>(Xtmp, wpack, h0, hfrag, rfrag, hnfrag,
                                            flags_h, flags_r, flags_n, bp, out);
}